// Round 18
// baseline (325.922 us; speedup 1.0000x reference)
//
#include <hip/hip_runtime.h>
#include <hip/hip_bf16.h>
#include <math.h>

#define N_ATOMS 500000
#define EPS 1e-5f
#define LDA 296   // bf16 elems per A row: 288 + 8 pad

// blocks per degree segment (1024 blocks), proportional to gather volume n_d*(d+1)
#define NB1 55
#define NB2 249
#define NB3 443
#define NB4 277
#define NBLK 1024

#define SEG_ELEMS 36864   // 288*128 bf16 per packed weight segment

typedef __attribute__((ext_vector_type(8))) short short8;
typedef __attribute__((ext_vector_type(8))) unsigned short ushort8v;
typedef __attribute__((ext_vector_type(4))) float floatx4;

__device__ __forceinline__ unsigned short f2bf(float f) {
    unsigned int x = __float_as_uint(f);
    x += 0x7FFF + ((x >> 16) & 1);          // round-to-nearest-even
    return (unsigned short)(x >> 16);
}

__device__ __forceinline__ float bf2f(unsigned short u) {
    return __uint_as_float(((unsigned int)u) << 16);
}

__device__ __forceinline__ float4 add4(float4 a, float4 b) {
    return make_float4(a.x + b.x, a.y + b.y, a.z + b.z, a.w + b.w);
}

__device__ __forceinline__ void st_bf4(unsigned short* p, float4 v) {
    ushort4 u;
    u.x = f2bf(v.x); u.y = f2bf(v.y); u.z = f2bf(v.z); u.w = f2bf(v.w);
    *reinterpret_cast<ushort4*>(p) = u;
}

// ---------------------------------------------------------------------------
// Convert atom table f32 -> bf16 (128 MB). NT loads; regular stores.
// ---------------------------------------------------------------------------
__global__ __launch_bounds__(256) void gdc_cvt(const float* __restrict__ a,
                                               unsigned short* __restrict__ o)
{
    const size_t nchunks = (size_t)N_ATOMS * 128 / 8;
    size_t idx = (size_t)blockIdx.x * 256 + threadIdx.x;
    const size_t stride = (size_t)gridDim.x * 256;
    for (; idx < nchunks; idx += stride) {
        floatx4 x0 = __builtin_nontemporal_load(((const floatx4*)a) + idx * 2);
        floatx4 x1 = __builtin_nontemporal_load(((const floatx4*)a) + idx * 2 + 1);
        ushort8v v;
        v[0] = f2bf(x0[0]); v[1] = f2bf(x0[1]); v[2] = f2bf(x0[2]); v[3] = f2bf(x0[3]);
        v[4] = f2bf(x1[0]); v[5] = f2bf(x1[1]); v[6] = f2bf(x1[2]); v[7] = f2bf(x1[3]);
        *(((ushort8v*)o) + idx) = v;
    }
}

// ---------------------------------------------------------------------------
// Pack weights into MFMA B-fragment layout, bf16.
// ---------------------------------------------------------------------------
__global__ __launch_bounds__(256) void gdc_pack(
    const float* __restrict__ W1, const float* __restrict__ W2,
    const float* __restrict__ W3, const float* __restrict__ W4,
    const float* __restrict__ Wself, unsigned short* __restrict__ packed)
{
    const int t = blockIdx.x * 256 + threadIdx.x;
    if (t >= 4 * 9 * 8 * 64) return;
    const int d    = t / 4608;
    const int r    = t % 4608;
    const int ks   = r / 512;
    const int nt   = (r % 512) / 64;
    const int lane = r % 64;
    const float* Wd = (d == 0) ? W1 : (d == 1) ? W2 : (d == 2) ? W3 : W4;
    const int col = nt * 16 + (lane & 15);
    short8 v;
    #pragma unroll
    for (int j = 0; j < 8; ++j) {
        const int k = ks * 32 + ((lane >> 4) << 3) + j;
        float w = 0.f;
        if (k < 144)      w = Wd[k * 128 + col];
        else if (k < 272) w = Wself[(k - 144) * 128 + col];
        v[j] = (short)f2bf(w);
    }
    *reinterpret_cast<short8*>(packed + (size_t)d * SEG_ELEMS
                               + ((size_t)(ks * 8 + nt) * 64 + lane) * 8) = v;
}

// ---------------------------------------------------------------------------
// 64-node-tile pipelined block loop: each thread gathers TWO nodes' slices
// (m and m+32) -> ~2x outstanding loads. Bond loads split by half-wave.
// BF: gather from bf16 table; XBF: bf16 x intermediate.
// ---------------------------------------------------------------------------
template <int DEG, bool BF, bool XBF>
__device__ __forceinline__ void block_loop(
    const float* __restrict__ atom, const unsigned short* __restrict__ abf,
    const float* __restrict__ bond,
    const int* __restrict__ aidx, const int* __restrict__ bidx,
    const unsigned short* __restrict__ pw,
    float* __restrict__ out, unsigned short* __restrict__ xout,
    unsigned short* __restrict__ A, int* __restrict__ own_lds,
    int n, int lb, int nb, int tid, int lane, int wv)
{
    const int m    = tid >> 4;           // node row 0..31 (pair with m+32)
    const int q16  = tid & 15;           // 8-elem k-slice
    const int qb   = (q16 & 7) * 2;      // bond col base
    const int ccol = lane & 15;
    const int crow = lane >> 4;
    const int nbase = wv * 16;

    short8 bfr[9];
    #pragma unroll
    for (int ks = 0; ks < 9; ++ks)
        bfr[ks] = ((const short8*)pw)[(ks * 8 + wv) * 64 + lane];

    float psum = 0.f, psq = 0.f;
    const int tiles = (n + 63) >> 6;
    const int nmax  = n - 1;

    ushort8v rawa[DEG + 1], rawc[DEG + 1];   // bf16 raw rows, nodes m / m+32
    float4 rafa[DEG + 1][2], rafc[DEG + 1][2]; // f32 fallback raw rows
    float2 rb[DEG];                           // bonds for this thread's node
    int nia[DEG + 1], nib[DEG + 1];           // prefetched NEXT-tile indices
    int owna_r, ownb_r;

    // ---- prologue: load tile lb's indices, issue its loads, prefetch next idx
    {
        const int ia = min((lb << 6) + m, nmax);
        const int ib = min((lb << 6) + 32 + m, nmax);
        const int* ar = aidx + (size_t)ia * (DEG + 1);
        const int* br = aidx + (size_t)ib * (DEG + 1);
        #pragma unroll
        for (int j = 0; j <= DEG; ++j) { nia[j] = ar[j]; nib[j] = br[j]; }
        owna_r = nia[0]; ownb_r = nib[0];
        #pragma unroll
        for (int j = 0; j <= DEG; ++j) {
            if (BF) {
                rawa[j] = *reinterpret_cast<const ushort8v*>(abf + (size_t)nia[j] * 128 + q16 * 8);
                rawc[j] = *reinterpret_cast<const ushort8v*>(abf + (size_t)nib[j] * 128 + q16 * 8);
            } else {
                const float4* pa = (const float4*)(atom + (size_t)nia[j] * 128 + q16 * 8);
                const float4* pc = (const float4*)(atom + (size_t)nib[j] * 128 + q16 * 8);
                rafa[j][0] = pa[0]; rafa[j][1] = pa[1];
                rafc[j][0] = pc[0]; rafc[j][1] = pc[1];
            }
        }
        {
            const int ibd = (q16 < 8) ? ia : ib;
            const int* bp = bidx + (size_t)ibd * DEG;
            #pragma unroll
            for (int j = 0; j < DEG; ++j)
                rb[j] = *(const float2*)(bond + (size_t)bp[j] * 16 + qb);
        }
        const int t1 = min(lb + nb, tiles - 1);
        const int ia1 = min((t1 << 6) + m, nmax);
        const int ib1 = min((t1 << 6) + 32 + m, nmax);
        const int* ar1 = aidx + (size_t)ia1 * (DEG + 1);
        const int* br1 = aidx + (size_t)ib1 * (DEG + 1);
        #pragma unroll
        for (int j = 0; j <= DEG; ++j) { nia[j] = ar1[j]; nib[j] = br1[j]; }
    }

    int k = 0;
    for (int t = lb; t < tiles; t += nb, ++k) {
        unsigned short* Ab = A + (k & 1) * (64 * LDA);
        int* ob = own_lds + (k & 1) * 64;

        // ---- commit tile t: sums -> LDS (vmcnt wait lands here) ----
        {
            unsigned short* rowa = Ab + m * LDA;
            unsigned short* rowc = Ab + (m + 32) * LDA;
            if (BF) {
                *reinterpret_cast<ushort8v*>(rowa + 144 + q16 * 8) = rawa[0];
                *reinterpret_cast<ushort8v*>(rowc + 144 + q16 * 8) = rawc[0];
                float sa[8], sc[8];
                #pragma unroll
                for (int e = 0; e < 8; ++e) { sa[e] = bf2f(rawa[0][e]); sc[e] = bf2f(rawc[0][e]); }
                #pragma unroll
                for (int j = 1; j <= DEG; ++j)
                    #pragma unroll
                    for (int e = 0; e < 8; ++e) { sa[e] += bf2f(rawa[j][e]); sc[e] += bf2f(rawc[j][e]); }
                ushort8v va, vc;
                #pragma unroll
                for (int e = 0; e < 8; ++e) { va[e] = f2bf(sa[e]); vc[e] = f2bf(sc[e]); }
                *reinterpret_cast<ushort8v*>(rowa + q16 * 8) = va;
                *reinterpret_cast<ushort8v*>(rowc + q16 * 8) = vc;
            } else {
                st_bf4(rowa + 144 + q16 * 8 + 0, rafa[0][0]);
                st_bf4(rowa + 144 + q16 * 8 + 4, rafa[0][1]);
                st_bf4(rowc + 144 + q16 * 8 + 0, rafc[0][0]);
                st_bf4(rowc + 144 + q16 * 8 + 4, rafc[0][1]);
                float4 a0 = rafa[0][0], a1 = rafa[0][1], c0 = rafc[0][0], c1 = rafc[0][1];
                #pragma unroll
                for (int j = 1; j <= DEG; ++j) {
                    a0 = add4(a0, rafa[j][0]); a1 = add4(a1, rafa[j][1]);
                    c0 = add4(c0, rafc[j][0]); c1 = add4(c1, rafc[j][1]);
                }
                st_bf4(rowa + q16 * 8 + 0, a0);
                st_bf4(rowa + q16 * 8 + 4, a1);
                st_bf4(rowc + q16 * 8 + 0, c0);
                st_bf4(rowc + q16 * 8 + 4, c1);
            }
            {
                unsigned short* rowbd = (q16 < 8) ? rowa : rowc;
                float bx = rb[0].x, by = rb[0].y;
                #pragma unroll
                for (int j = 1; j < DEG; ++j) { bx += rb[j].x; by += rb[j].y; }
                rowbd[128 + qb]     = f2bf(bx);
                rowbd[128 + qb + 1] = f2bf(by);
            }
            if (q16 == 0) { ob[m] = owna_r; ob[m + 32] = ownb_r; }
        }
        __syncthreads();

        // ---- issue tile t+nb's loads (block-uniform branch) ----
        if (t + nb < tiles) {
            const int ia = min(((t + nb) << 6) + m, nmax);
            const int ib = min(((t + nb) << 6) + 32 + m, nmax);
            owna_r = nia[0]; ownb_r = nib[0];
            #pragma unroll
            for (int j = 0; j <= DEG; ++j) {
                if (BF) {
                    rawa[j] = *reinterpret_cast<const ushort8v*>(abf + (size_t)nia[j] * 128 + q16 * 8);
                    rawc[j] = *reinterpret_cast<const ushort8v*>(abf + (size_t)nib[j] * 128 + q16 * 8);
                } else {
                    const float4* pa = (const float4*)(atom + (size_t)nia[j] * 128 + q16 * 8);
                    const float4* pc = (const float4*)(atom + (size_t)nib[j] * 128 + q16 * 8);
                    rafa[j][0] = pa[0]; rafa[j][1] = pa[1];
                    rafc[j][0] = pc[0]; rafc[j][1] = pc[1];
                }
            }
            {
                const int ibd = (q16 < 8) ? ia : ib;
                const int* bp = bidx + (size_t)ibd * DEG;
                #pragma unroll
                for (int j = 0; j < DEG; ++j)
                    rb[j] = *(const float2*)(bond + (size_t)bp[j] * 16 + qb);
            }
            const int t2 = min(t + 2 * nb, tiles - 1);
            const int ia2 = min((t2 << 6) + m, nmax);
            const int ib2 = min((t2 << 6) + 32 + m, nmax);
            const int* ar2 = aidx + (size_t)ia2 * (DEG + 1);
            const int* br2 = aidx + (size_t)ib2 * (DEG + 1);
            #pragma unroll
            for (int j = 0; j <= DEG; ++j) { nia[j] = ar2[j]; nib[j] = br2[j]; }
        }

        // ---- MFMA tile t: 4 m-tiles x 9 ks ----
        floatx4 acc[4];
        #pragma unroll
        for (int mt = 0; mt < 4; ++mt) acc[mt] = (floatx4){0.f, 0.f, 0.f, 0.f};
        #pragma unroll
        for (int ks = 0; ks < 9; ++ks) {
            #pragma unroll
            for (int mt = 0; mt < 4; ++mt) {
                const short8 af = *(const short8*)&Ab[(mt * 16 + ccol) * LDA + ks * 32 + (crow << 3)];
                acc[mt] = __builtin_amdgcn_mfma_f32_16x16x32_bf16(af, bfr[ks], acc[mt], 0, 0, 0);
            }
        }

        // ---- scatter + BN partials ----
        const int i0 = t << 6;
        #pragma unroll
        for (int mt = 0; mt < 4; ++mt) {
            const int4 o4 = *reinterpret_cast<const int4*>(&ob[mt * 16 + crow * 4]);
            const int owns[4] = {o4.x, o4.y, o4.z, o4.w};
            #pragma unroll
            for (int rr = 0; rr < 4; ++rr) {
                const int row = mt * 16 + crow * 4 + rr;
                if (i0 + row < n) {
                    const float v = acc[mt][rr];
                    if (XBF) {
                        const unsigned short u = f2bf(v);
                        const float vr = bf2f(u);
                        xout[(size_t)owns[rr] * 128 + nbase + ccol] = u;
                        psum += vr; psq += vr * vr;
                    } else {
                        out[(size_t)owns[rr] * 128 + nbase + ccol] = v;
                        psum += v; psq += v * v;
                    }
                }
            }
        }
    }

    __syncthreads();

    float* redS = reinterpret_cast<float*>(A);
    float* redQ = redS + 128;
    {
        float s = psum, q = psq;
        s += __shfl_xor(s, 16, 64); s += __shfl_xor(s, 32, 64);
        q += __shfl_xor(q, 16, 64); q += __shfl_xor(q, 32, 64);
        if (lane < 16) {
            redS[nbase + lane] = s;
            redQ[nbase + lane] = q;
        }
    }
}

// ---------------------------------------------------------------------------
// Fused kernel: 512 threads = 8 waves; 76.3 KB LDS (double-buffered 64-row A).
// ---------------------------------------------------------------------------
template <bool BF, bool XBF>
__global__ __launch_bounds__(512, 4) void gdc_mfma(
    const float* __restrict__ atom, const unsigned short* __restrict__ abf,
    const float* __restrict__ bond,
    const int* __restrict__ a1, const int* __restrict__ b1,
    const int* __restrict__ a2, const int* __restrict__ b2,
    const int* __restrict__ a3, const int* __restrict__ b3,
    const int* __restrict__ a4, const int* __restrict__ b4,
    const unsigned short* __restrict__ packedW,
    float* __restrict__ out, unsigned short* __restrict__ xout,
    float* __restrict__ sumPart, float* __restrict__ sqPart)
{
    __shared__ __align__(16) unsigned short A[2 * 64 * LDA];   // 75776 B
    __shared__ __align__(16) int own_lds[2 * 64];

    const int tid  = threadIdx.x;
    const int wv   = tid >> 6;
    const int lane = tid & 63;
    const int blk  = blockIdx.x;

    int n, lb, nb, deg;
    const int* aidx; const int* bidx;
    if (blk < NB1)                 { deg = 1; n =  50000; lb = blk;                 nb = NB1; aidx = a1; bidx = b1; }
    else if (blk < NB1+NB2)        { deg = 2; n = 150000; lb = blk-NB1;             nb = NB2; aidx = a2; bidx = b2; }
    else if (blk < NB1+NB2+NB3)    { deg = 3; n = 200000; lb = blk-(NB1+NB2);       nb = NB3; aidx = a3; bidx = b3; }
    else                           { deg = 4; n = 100000; lb = blk-(NB1+NB2+NB3);   nb = NB4; aidx = a4; bidx = b4; }

    const unsigned short* pw = packedW + (size_t)(deg - 1) * SEG_ELEMS;

    // zero K-pad cols 272..287 of both buffers once
    {
        const int mm = tid >> 3, qq = tid & 7;
        ushort2 z; z.x = 0; z.y = 0;
        *reinterpret_cast<ushort2*>(&A[mm * LDA + 272 + qq * 2]) = z;
        *reinterpret_cast<ushort2*>(&A[64 * LDA + mm * LDA + 272 + qq * 2]) = z;
    }
    __syncthreads();

    switch (deg) {
    case 1:  block_loop<1, BF, XBF>(atom, abf, bond, aidx, bidx, pw, out, xout, A, own_lds, n, lb, nb, tid, lane, wv); break;
    case 2:  block_loop<2, BF, XBF>(atom, abf, bond, aidx, bidx, pw, out, xout, A, own_lds, n, lb, nb, tid, lane, wv); break;
    case 3:  block_loop<3, BF, XBF>(atom, abf, bond, aidx, bidx, pw, out, xout, A, own_lds, n, lb, nb, tid, lane, wv); break;
    default: block_loop<4, BF, XBF>(atom, abf, bond, aidx, bidx, pw, out, xout, A, own_lds, n, lb, nb, tid, lane, wv); break;
    }

    __syncthreads();
    const float* redS = reinterpret_cast<const float*>(A);
    if (tid < 128)      sumPart[(size_t)blk * 128 + tid] = redS[tid];
    else if (tid < 256) sqPart[(size_t)blk * 128 + (tid - 128)] = redS[tid];
}

// ---------------------------------------------------------------------------
// Reduce NBLK partials per channel -> mean, invstd (deterministic).
// ---------------------------------------------------------------------------
__global__ void gdc_stats(const float* __restrict__ sumPart,
                          const float* __restrict__ sqPart,
                          float* __restrict__ mv)
{
    const int c = blockIdx.x;
    const int j = threadIdx.x;
    __shared__ float rs[256], rq[256];
    float s = 0.f, q = 0.f;
    for (int b = j; b < NBLK; b += 256) {
        s += sumPart[(size_t)b * 128 + c];
        q += sqPart[(size_t)b * 128 + c];
    }
    rs[j] = s; rq[j] = q;
    __syncthreads();
    for (int off = 128; off > 0; off >>= 1) {
        if (j < off) { rs[j] += rs[j + off]; rq[j] += rq[j + off]; }
        __syncthreads();
    }
    if (j == 0) {
        const float mean = rs[0] / (float)N_ATOMS;
        const float var  = rq[0] / (float)N_ATOMS - mean * mean;
        mv[c]       = mean;
        mv[128 + c] = rsqrtf(var + EPS);
    }
}

// ---------------------------------------------------------------------------
// Normalize + ReLU from bf16 intermediate -> f32 out (NT stores).
// ---------------------------------------------------------------------------
__global__ __launch_bounds__(256) void gdc_norm_bf(const unsigned short* __restrict__ x,
                                                   float* __restrict__ out,
                                                   const float* __restrict__ mv)
{
    const size_t total8 = (size_t)N_ATOMS * 128 / 8;
    size_t idx = (size_t)blockIdx.x * 256 + threadIdx.x;
    const int c = (int)((idx * 8) & 127);
    const float4 m0 = *(const float4*)(mv + c);
    const float4 m1 = *(const float4*)(mv + c + 4);
    const float4 i0 = *(const float4*)(mv + 128 + c);
    const float4 i1 = *(const float4*)(mv + 128 + c + 4);
    const size_t stride = (size_t)gridDim.x * 256;
    for (; idx < total8; idx += stride) {
        const ushort8v v = *(((const ushort8v*)x) + idx);
        floatx4 o0, o1;
        o0[0] = fmaxf(0.f, (bf2f(v[0]) - m0.x) * i0.x);
        o0[1] = fmaxf(0.f, (bf2f(v[1]) - m0.y) * i0.y);
        o0[2] = fmaxf(0.f, (bf2f(v[2]) - m0.z) * i0.z);
        o0[3] = fmaxf(0.f, (bf2f(v[3]) - m0.w) * i0.w);
        o1[0] = fmaxf(0.f, (bf2f(v[4]) - m1.x) * i1.x);
        o1[1] = fmaxf(0.f, (bf2f(v[5]) - m1.y) * i1.y);
        o1[2] = fmaxf(0.f, (bf2f(v[6]) - m1.z) * i1.z);
        o1[3] = fmaxf(0.f, (bf2f(v[7]) - m1.w) * i1.w);
        __builtin_nontemporal_store(o0, ((floatx4*)out) + idx * 2);
        __builtin_nontemporal_store(o1, ((floatx4*)out) + idx * 2 + 1);
    }
}

// ---------------------------------------------------------------------------
// In-place normalize + ReLU (f32 fallback path).
// ---------------------------------------------------------------------------
__global__ __launch_bounds__(256) void gdc_norm(float* __restrict__ out,
                                                const float* __restrict__ mv)
{
    const size_t total4 = (size_t)N_ATOMS * 128 / 4;
    size_t idx = (size_t)blockIdx.x * 256 + threadIdx.x;
    const int c = (int)((idx * 4) & 127);
    const float4 m  = *(const float4*)(mv + c);
    const float4 iv = *(const float4*)(mv + 128 + c);
    const size_t stride = (size_t)gridDim.x * 256;
    for (; idx < total4; idx += stride) {
        floatx4 v = __builtin_nontemporal_load(((const floatx4*)out) + idx);
        v[0] = fmaxf(0.f, (v[0] - m.x) * iv.x);
        v[1] = fmaxf(0.f, (v[1] - m.y) * iv.y);
        v[2] = fmaxf(0.f, (v[2] - m.z) * iv.z);
        v[3] = fmaxf(0.f, (v[3] - m.w) * iv.w);
        __builtin_nontemporal_store(v, ((floatx4*)out) + idx);
    }
}

extern "C" void kernel_launch(void* const* d_in, const int* in_sizes, int n_in,
                              void* d_out, int out_size, void* d_ws, size_t ws_size,
                              hipStream_t stream) {
    const float* atom  = (const float*)d_in[0];
    const float* bond  = (const float*)d_in[1];
    const int*   a1    = (const int*)d_in[2];
    const int*   b1    = (const int*)d_in[3];
    const int*   a2    = (const int*)d_in[4];
    const int*   b2    = (const int*)d_in[5];
    const int*   a3    = (const int*)d_in[6];
    const int*   b3    = (const int*)d_in[7];
    const int*   a4    = (const int*)d_in[8];
    const int*   b4    = (const int*)d_in[9];
    const float* Wself = (const float*)d_in[10];
    const float* W1    = (const float*)d_in[11];
    const float* W2    = (const float*)d_in[12];
    const float* W3    = (const float*)d_in[13];
    const float* W4    = (const float*)d_in[14];
    float* out = (float*)d_out;

    const size_t abf_bytes  = (size_t)N_ATOMS * 128 * sizeof(unsigned short); // 128 MB
    const size_t xbf_bytes  = abf_bytes;                                      // 128 MB
    const size_t pack_bytes = 4 * SEG_ELEMS * sizeof(unsigned short);
    const size_t part_bytes = (size_t)NBLK * 128 * sizeof(float);
    const size_t need_full  = abf_bytes + xbf_bytes + pack_bytes + 2 * part_bytes + 1024;
    const size_t need_bf    = abf_bytes + pack_bytes + 2 * part_bytes + 1024;

    if (ws_size >= need_full) {
        // ws: atom_bf | x_bf | packedW | sumPart | sqPart | mv
        char* p = (char*)d_ws;
        unsigned short* abf     = (unsigned short*)p;  p += abf_bytes;
        unsigned short* xbf     = (unsigned short*)p;  p += xbf_bytes;
        unsigned short* packedW = (unsigned short*)p;  p += pack_bytes;
        float* sumPart = (float*)p;                    p += part_bytes;
        float* sqPart  = (float*)p;                    p += part_bytes;
        float* mv      = (float*)p;

        hipLaunchKernelGGL(gdc_cvt, dim3(2048), dim3(256), 0, stream, atom, abf);
        hipLaunchKernelGGL(gdc_pack, dim3((4*9*8*64 + 255)/256), dim3(256), 0, stream,
                           W1, W2, W3, W4, Wself, packedW);
        hipLaunchKernelGGL((gdc_mfma<true, true>), dim3(NBLK), dim3(512), 0, stream,
                           atom, abf, bond, a1, b1, a2, b2, a3, b3, a4, b4,
                           packedW, out, xbf, sumPart, sqPart);
        hipLaunchKernelGGL(gdc_stats, dim3(128), dim3(256), 0, stream,
                           sumPart, sqPart, mv);
        hipLaunchKernelGGL(gdc_norm_bf, dim3(2048), dim3(256), 0, stream, xbf, out, mv);
    } else if (ws_size >= need_bf) {
        // ws: atom_bf | packedW | sumPart | sqPart | mv
        char* p = (char*)d_ws;
        unsigned short* abf     = (unsigned short*)p;  p += abf_bytes;
        unsigned short* packedW = (unsigned short*)p;  p += pack_bytes;
        float* sumPart = (float*)p;                    p += part_bytes;
        float* sqPart  = (float*)p;                    p += part_bytes;
        float* mv      = (float*)p;

        hipLaunchKernelGGL(gdc_cvt, dim3(2048), dim3(256), 0, stream, atom, abf);
        hipLaunchKernelGGL(gdc_pack, dim3((4*9*8*64 + 255)/256), dim3(256), 0, stream,
                           W1, W2, W3, W4, Wself, packedW);
        hipLaunchKernelGGL((gdc_mfma<true, false>), dim3(NBLK), dim3(512), 0, stream,
                           atom, abf, bond, a1, b1, a2, b2, a3, b3, a4, b4,
                           packedW, out, (unsigned short*)nullptr, sumPart, sqPart);
        hipLaunchKernelGGL(gdc_stats, dim3(128), dim3(256), 0, stream,
                           sumPart, sqPart, mv);
        hipLaunchKernelGGL(gdc_norm, dim3(2048), dim3(256), 0, stream, out, mv);
    } else {
        // minimal fallback: f32 gather, f32 in-place norm
        char* p = (char*)d_ws;
        unsigned short* packedW = (unsigned short*)p;  p += pack_bytes;
        float* sumPart = (float*)p;                    p += part_bytes;
        float* sqPart  = (float*)p;                    p += part_bytes;
        float* mv      = (float*)p;

        hipLaunchKernelGGL(gdc_pack, dim3((4*9*8*64 + 255)/256), dim3(256), 0, stream,
                           W1, W2, W3, W4, Wself, packedW);
        hipLaunchKernelGGL((gdc_mfma<false, false>), dim3(NBLK), dim3(512), 0, stream,
                           atom, (const unsigned short*)nullptr, bond,
                           a1, b1, a2, b2, a3, b3, a4, b4,
                           packedW, out, (unsigned short*)nullptr, sumPart, sqPart);
        hipLaunchKernelGGL(gdc_stats, dim3(128), dim3(256), 0, stream,
                           sumPart, sqPart, mv);
        hipLaunchKernelGGL(gdc_norm, dim3(2048), dim3(256), 0, stream, out, mv);
    }
}

// Round 19
// 301.836 us; speedup vs baseline: 1.0798x; 1.0798x over previous
//
#include <hip/hip_runtime.h>
#include <hip/hip_bf16.h>
#include <math.h>

#define N_ATOMS 500000
#define EPS 1e-5f
#define LDA 296   // bf16 elems per A row: 288 + 8 pad

// blocks per degree segment (2048 blocks = 8 queued/CU), ~equal gather work per block
#define NB1 110
#define NB2 498
#define NB3 886
#define NB4 554
#define NBLK 2048

#define SEG_ELEMS 36864   // 288*128 bf16 per packed weight segment

typedef __attribute__((ext_vector_type(8))) short short8;
typedef __attribute__((ext_vector_type(8))) unsigned short ushort8v;
typedef __attribute__((ext_vector_type(4))) float floatx4;

__device__ __forceinline__ unsigned short f2bf(float f) {
    unsigned int x = __float_as_uint(f);
    x += 0x7FFF + ((x >> 16) & 1);          // round-to-nearest-even
    return (unsigned short)(x >> 16);
}

__device__ __forceinline__ float bf2f(unsigned short u) {
    return __uint_as_float(((unsigned int)u) << 16);
}

__device__ __forceinline__ float4 add4(float4 a, float4 b) {
    return make_float4(a.x + b.x, a.y + b.y, a.z + b.z, a.w + b.w);
}

__device__ __forceinline__ void st_bf4(unsigned short* p, float4 v) {
    ushort4 u;
    u.x = f2bf(v.x); u.y = f2bf(v.y); u.z = f2bf(v.z); u.w = f2bf(v.w);
    *reinterpret_cast<ushort4*>(p) = u;
}

// ---------------------------------------------------------------------------
// Convert atom table f32 -> bf16 (128 MB). NT loads; regular stores.
// ---------------------------------------------------------------------------
__global__ __launch_bounds__(256) void gdc_cvt(const float* __restrict__ a,
                                               unsigned short* __restrict__ o)
{
    const size_t nchunks = (size_t)N_ATOMS * 128 / 8;
    size_t idx = (size_t)blockIdx.x * 256 + threadIdx.x;
    const size_t stride = (size_t)gridDim.x * 256;
    for (; idx < nchunks; idx += stride) {
        floatx4 x0 = __builtin_nontemporal_load(((const floatx4*)a) + idx * 2);
        floatx4 x1 = __builtin_nontemporal_load(((const floatx4*)a) + idx * 2 + 1);
        ushort8v v;
        v[0] = f2bf(x0[0]); v[1] = f2bf(x0[1]); v[2] = f2bf(x0[2]); v[3] = f2bf(x0[3]);
        v[4] = f2bf(x1[0]); v[5] = f2bf(x1[1]); v[6] = f2bf(x1[2]); v[7] = f2bf(x1[3]);
        *(((ushort8v*)o) + idx) = v;
    }
}

// ---------------------------------------------------------------------------
// Pack weights into MFMA B-fragment layout, bf16.
// ---------------------------------------------------------------------------
__global__ __launch_bounds__(256) void gdc_pack(
    const float* __restrict__ W1, const float* __restrict__ W2,
    const float* __restrict__ W3, const float* __restrict__ W4,
    const float* __restrict__ Wself, unsigned short* __restrict__ packed)
{
    const int t = blockIdx.x * 256 + threadIdx.x;
    if (t >= 4 * 9 * 8 * 64) return;
    const int d    = t / 4608;
    const int r    = t % 4608;
    const int ks   = r / 512;
    const int nt   = (r % 512) / 64;
    const int lane = r % 64;
    const float* Wd = (d == 0) ? W1 : (d == 1) ? W2 : (d == 2) ? W3 : W4;
    const int col = nt * 16 + (lane & 15);
    short8 v;
    #pragma unroll
    for (int j = 0; j < 8; ++j) {
        const int k = ks * 32 + ((lane >> 4) << 3) + j;
        float w = 0.f;
        if (k < 144)      w = Wd[k * 128 + col];
        else if (k < 272) w = Wself[(k - 144) * 128 + col];
        v[j] = (short)f2bf(w);
    }
    *reinterpret_cast<short8*>(packed + (size_t)d * SEG_ELEMS
                               + ((size_t)(ks * 8 + nt) * 64 + lane) * 8) = v;
}

// ---------------------------------------------------------------------------
// Pipelined block loop. BF: gather from bf16 atom table. XBF: store x as
// bf16 into xout (stats on rounded values); else f32 into out.
// ---------------------------------------------------------------------------
template <int DEG, bool BF, bool XBF>
__device__ __forceinline__ void block_loop(
    const float* __restrict__ atom, const unsigned short* __restrict__ abf,
    const float* __restrict__ bond,
    const int* __restrict__ aidx, const int* __restrict__ bidx,
    const unsigned short* __restrict__ pw,
    float* __restrict__ out, unsigned short* __restrict__ xout,
    unsigned short* __restrict__ A, int* __restrict__ own_lds,
    int n, int lb, int nb, int tid, int lane, int wv)
{
    const int m    = tid >> 4;           // node row 0..31
    const int q16  = tid & 15;           // 8-elem k-slice
    const int ccol = lane & 15;
    const int crow = lane >> 4;
    const int nbase = wv * 16;

    short8 bfr[9];
    #pragma unroll
    for (int ks = 0; ks < 9; ++ks)
        bfr[ks] = ((const short8*)pw)[(ks * 8 + wv) * 64 + lane];

    float psum = 0.f, psq = 0.f;
    const int tiles = (n + 31) >> 5;
    const int nmax  = n - 1;

    ushort8v rawb[DEG + 1];
    float4 rawf[DEG + 1][2];
    float2 rb[DEG];
    int own_r;
    int ni[DEG + 1];

    // ---- prologue ----
    {
        const int i = min((lb << 5) + m, nmax);
        const int* ar = aidx + (size_t)i * (DEG + 1);
        #pragma unroll
        for (int j = 0; j <= DEG; ++j) ni[j] = ar[j];
        own_r = ni[0];
        #pragma unroll
        for (int j = 0; j <= DEG; ++j) {
            if (BF) {
                rawb[j] = *reinterpret_cast<const ushort8v*>(abf + (size_t)ni[j] * 128 + q16 * 8);
            } else {
                const float4* pp = (const float4*)(atom + (size_t)ni[j] * 128 + q16 * 8);
                rawf[j][0] = pp[0]; rawf[j][1] = pp[1];
            }
        }
        if (q16 < 8) {
            const int* br = bidx + (size_t)i * DEG;
            #pragma unroll
            for (int j = 0; j < DEG; ++j)
                rb[j] = *(const float2*)(bond + (size_t)br[j] * 16 + q16 * 2);
        }
        const int t1 = min(lb + nb, tiles - 1);
        const int i1 = min((t1 << 5) + m, nmax);
        const int* ar1 = aidx + (size_t)i1 * (DEG + 1);
        #pragma unroll
        for (int j = 0; j <= DEG; ++j) ni[j] = ar1[j];
    }

    int k = 0;
    for (int t = lb; t < tiles; t += nb, ++k) {
        unsigned short* Ab = A + (k & 1) * (32 * LDA);
        int* ob = own_lds + (k & 1) * 32;

        // ---- commit tile t ----
        {
            unsigned short* rowp = Ab + m * LDA;
            if (BF) {
                *reinterpret_cast<ushort8v*>(rowp + 144 + q16 * 8) = rawb[0];
                float s[8];
                #pragma unroll
                for (int e = 0; e < 8; ++e) s[e] = bf2f(rawb[0][e]);
                #pragma unroll
                for (int j = 1; j <= DEG; ++j)
                    #pragma unroll
                    for (int e = 0; e < 8; ++e) s[e] += bf2f(rawb[j][e]);
                ushort8v sm;
                #pragma unroll
                for (int e = 0; e < 8; ++e) sm[e] = f2bf(s[e]);
                *reinterpret_cast<ushort8v*>(rowp + q16 * 8) = sm;
            } else {
                st_bf4(rowp + 144 + q16 * 8 + 0, rawf[0][0]);
                st_bf4(rowp + 144 + q16 * 8 + 4, rawf[0][1]);
                float4 s0 = rawf[0][0], s1 = rawf[0][1];
                #pragma unroll
                for (int j = 1; j <= DEG; ++j) {
                    s0 = add4(s0, rawf[j][0]); s1 = add4(s1, rawf[j][1]);
                }
                st_bf4(rowp + q16 * 8 + 0, s0);
                st_bf4(rowp + q16 * 8 + 4, s1);
            }
            if (q16 < 8) {
                float bx = rb[0].x, by = rb[0].y;
                #pragma unroll
                for (int j = 1; j < DEG; ++j) { bx += rb[j].x; by += rb[j].y; }
                rowp[128 + q16 * 2]     = f2bf(bx);
                rowp[128 + q16 * 2 + 1] = f2bf(by);
            }
            if (q16 == 0) ob[m] = own_r;
        }
        __syncthreads();

        // ---- issue tile t+nb's loads ----
        if (t + nb < tiles) {
            const int i = min(((t + nb) << 5) + m, nmax);
            own_r = ni[0];
            #pragma unroll
            for (int j = 0; j <= DEG; ++j) {
                if (BF) {
                    rawb[j] = *reinterpret_cast<const ushort8v*>(abf + (size_t)ni[j] * 128 + q16 * 8);
                } else {
                    const float4* pp = (const float4*)(atom + (size_t)ni[j] * 128 + q16 * 8);
                    rawf[j][0] = pp[0]; rawf[j][1] = pp[1];
                }
            }
            if (q16 < 8) {
                const int* br = bidx + (size_t)i * DEG;
                #pragma unroll
                for (int j = 0; j < DEG; ++j)
                    rb[j] = *(const float2*)(bond + (size_t)br[j] * 16 + q16 * 2);
            }
            const int t2 = min(t + 2 * nb, tiles - 1);
            const int i2 = min((t2 << 5) + m, nmax);
            const int* ar2 = aidx + (size_t)i2 * (DEG + 1);
            #pragma unroll
            for (int j = 0; j <= DEG; ++j) ni[j] = ar2[j];
        }

        // ---- MFMA tile t ----
        floatx4 acc0 = (floatx4){0.f, 0.f, 0.f, 0.f};
        floatx4 acc1 = (floatx4){0.f, 0.f, 0.f, 0.f};
        #pragma unroll
        for (int ks = 0; ks < 9; ++ks) {
            const short8 af0 = *(const short8*)&Ab[ccol * LDA + ks * 32 + (crow << 3)];
            const short8 af1 = *(const short8*)&Ab[(16 + ccol) * LDA + ks * 32 + (crow << 3)];
            acc0 = __builtin_amdgcn_mfma_f32_16x16x32_bf16(af0, bfr[ks], acc0, 0, 0, 0);
            acc1 = __builtin_amdgcn_mfma_f32_16x16x32_bf16(af1, bfr[ks], acc1, 0, 0, 0);
        }

        // ---- scatter + BN partials ----
        const int i0 = t << 5;
        const int4 o0 = *reinterpret_cast<const int4*>(&ob[crow * 4]);
        const int4 o1 = *reinterpret_cast<const int4*>(&ob[16 + crow * 4]);
        const int owns0[4] = {o0.x, o0.y, o0.z, o0.w};
        const int owns1[4] = {o1.x, o1.y, o1.z, o1.w};
        #pragma unroll
        for (int rr = 0; rr < 4; ++rr) {
            const int row = crow * 4 + rr;
            if (i0 + row < n) {
                const float v = acc0[rr];
                if (XBF) {
                    const unsigned short u = f2bf(v);
                    const float vr = bf2f(u);
                    xout[(size_t)owns0[rr] * 128 + nbase + ccol] = u;
                    psum += vr; psq += vr * vr;
                } else {
                    out[(size_t)owns0[rr] * 128 + nbase + ccol] = v;
                    psum += v; psq += v * v;
                }
            }
            if (i0 + 16 + row < n) {
                const float v = acc1[rr];
                if (XBF) {
                    const unsigned short u = f2bf(v);
                    const float vr = bf2f(u);
                    xout[(size_t)owns1[rr] * 128 + nbase + ccol] = u;
                    psum += vr; psq += vr * vr;
                } else {
                    out[(size_t)owns1[rr] * 128 + nbase + ccol] = v;
                    psum += v; psq += v * v;
                }
            }
        }
    }

    __syncthreads();

    float* redS = reinterpret_cast<float*>(A);
    float* redQ = redS + 128;
    {
        float s = psum, q = psq;
        s += __shfl_xor(s, 16, 64); s += __shfl_xor(s, 32, 64);
        q += __shfl_xor(q, 16, 64); q += __shfl_xor(q, 32, 64);
        if (lane < 16) {
            redS[nbase + lane] = s;
            redQ[nbase + lane] = q;
        }
    }
}

// ---------------------------------------------------------------------------
// Fused kernel: 512 threads = 8 waves; 38.1 KB LDS (double-buffered A).
// ---------------------------------------------------------------------------
template <bool BF, bool XBF>
__global__ __launch_bounds__(512, 4) void gdc_mfma(
    const float* __restrict__ atom, const unsigned short* __restrict__ abf,
    const float* __restrict__ bond,
    const int* __restrict__ a1, const int* __restrict__ b1,
    const int* __restrict__ a2, const int* __restrict__ b2,
    const int* __restrict__ a3, const int* __restrict__ b3,
    const int* __restrict__ a4, const int* __restrict__ b4,
    const unsigned short* __restrict__ packedW,
    float* __restrict__ out, unsigned short* __restrict__ xout,
    float* __restrict__ sumPart, float* __restrict__ sqPart)
{
    __shared__ __align__(16) unsigned short A[2 * 32 * LDA];
    __shared__ __align__(16) int own_lds[2 * 32];

    const int tid  = threadIdx.x;
    const int wv   = tid >> 6;
    const int lane = tid & 63;
    const int blk  = blockIdx.x;

    int n, lb, nb, deg;
    const int* aidx; const int* bidx;
    if (blk < NB1)                 { deg = 1; n =  50000; lb = blk;                 nb = NB1; aidx = a1; bidx = b1; }
    else if (blk < NB1+NB2)        { deg = 2; n = 150000; lb = blk-NB1;             nb = NB2; aidx = a2; bidx = b2; }
    else if (blk < NB1+NB2+NB3)    { deg = 3; n = 200000; lb = blk-(NB1+NB2);       nb = NB3; aidx = a3; bidx = b3; }
    else                           { deg = 4; n = 100000; lb = blk-(NB1+NB2+NB3);   nb = NB4; aidx = a4; bidx = b4; }

    const unsigned short* pw = packedW + (size_t)(deg - 1) * SEG_ELEMS;

    {
        const int mm = tid >> 4, qq = tid & 15;
        if (qq >= 8) {
            ushort2 z; z.x = 0; z.y = 0;
            *reinterpret_cast<ushort2*>(&A[mm * LDA + 272 + (qq - 8) * 2]) = z;
            *reinterpret_cast<ushort2*>(&A[32 * LDA + mm * LDA + 272 + (qq - 8) * 2]) = z;
        }
    }
    __syncthreads();

    switch (deg) {
    case 1:  block_loop<1, BF, XBF>(atom, abf, bond, aidx, bidx, pw, out, xout, A, own_lds, n, lb, nb, tid, lane, wv); break;
    case 2:  block_loop<2, BF, XBF>(atom, abf, bond, aidx, bidx, pw, out, xout, A, own_lds, n, lb, nb, tid, lane, wv); break;
    case 3:  block_loop<3, BF, XBF>(atom, abf, bond, aidx, bidx, pw, out, xout, A, own_lds, n, lb, nb, tid, lane, wv); break;
    default: block_loop<4, BF, XBF>(atom, abf, bond, aidx, bidx, pw, out, xout, A, own_lds, n, lb, nb, tid, lane, wv); break;
    }

    __syncthreads();
    const float* redS = reinterpret_cast<const float*>(A);
    if (tid < 128)      sumPart[(size_t)blk * 128 + tid] = redS[tid];
    else if (tid < 256) sqPart[(size_t)blk * 128 + (tid - 128)] = redS[tid];
}

// ---------------------------------------------------------------------------
// Reduce NBLK partials per channel -> mean, invstd (deterministic).
// ---------------------------------------------------------------------------
__global__ void gdc_stats(const float* __restrict__ sumPart,
                          const float* __restrict__ sqPart,
                          float* __restrict__ mv)
{
    const int c = blockIdx.x;
    const int j = threadIdx.x;
    __shared__ float rs[256], rq[256];
    float s = 0.f, q = 0.f;
    for (int b = j; b < NBLK; b += 256) {
        s += sumPart[(size_t)b * 128 + c];
        q += sqPart[(size_t)b * 128 + c];
    }
    rs[j] = s; rq[j] = q;
    __syncthreads();
    for (int off = 128; off > 0; off >>= 1) {
        if (j < off) { rs[j] += rs[j + off]; rq[j] += rq[j + off]; }
        __syncthreads();
    }
    if (j == 0) {
        const float mean = rs[0] / (float)N_ATOMS;
        const float var  = rq[0] / (float)N_ATOMS - mean * mean;
        mv[c]       = mean;
        mv[128 + c] = rsqrtf(var + EPS);
    }
}

// ---------------------------------------------------------------------------
// Normalize + ReLU from bf16 intermediate -> f32 out (NT stores).
// ---------------------------------------------------------------------------
__global__ __launch_bounds__(256) void gdc_norm_bf(const unsigned short* __restrict__ x,
                                                   float* __restrict__ out,
                                                   const float* __restrict__ mv)
{
    const size_t total8 = (size_t)N_ATOMS * 128 / 8;
    size_t idx = (size_t)blockIdx.x * 256 + threadIdx.x;
    const int c = (int)((idx * 8) & 127);
    const float4 m0 = *(const float4*)(mv + c);
    const float4 m1 = *(const float4*)(mv + c + 4);
    const float4 i0 = *(const float4*)(mv + 128 + c);
    const float4 i1 = *(const float4*)(mv + 128 + c + 4);
    const size_t stride = (size_t)gridDim.x * 256;
    for (; idx < total8; idx += stride) {
        const ushort8v v = *(((const ushort8v*)x) + idx);
        floatx4 o0, o1;
        o0[0] = fmaxf(0.f, (bf2f(v[0]) - m0.x) * i0.x);
        o0[1] = fmaxf(0.f, (bf2f(v[1]) - m0.y) * i0.y);
        o0[2] = fmaxf(0.f, (bf2f(v[2]) - m0.z) * i0.z);
        o0[3] = fmaxf(0.f, (bf2f(v[3]) - m0.w) * i0.w);
        o1[0] = fmaxf(0.f, (bf2f(v[4]) - m1.x) * i1.x);
        o1[1] = fmaxf(0.f, (bf2f(v[5]) - m1.y) * i1.y);
        o1[2] = fmaxf(0.f, (bf2f(v[6]) - m1.z) * i1.z);
        o1[3] = fmaxf(0.f, (bf2f(v[7]) - m1.w) * i1.w);
        __builtin_nontemporal_store(o0, ((floatx4*)out) + idx * 2);
        __builtin_nontemporal_store(o1, ((floatx4*)out) + idx * 2 + 1);
    }
}

// ---------------------------------------------------------------------------
// In-place normalize + ReLU (f32 fallback path).
// ---------------------------------------------------------------------------
__global__ __launch_bounds__(256) void gdc_norm(float* __restrict__ out,
                                                const float* __restrict__ mv)
{
    const size_t total4 = (size_t)N_ATOMS * 128 / 4;
    size_t idx = (size_t)blockIdx.x * 256 + threadIdx.x;
    const int c = (int)((idx * 4) & 127);
    const float4 m  = *(const float4*)(mv + c);
    const float4 iv = *(const float4*)(mv + 128 + c);
    const size_t stride = (size_t)gridDim.x * 256;
    for (; idx < total4; idx += stride) {
        floatx4 v = __builtin_nontemporal_load(((const floatx4*)out) + idx);
        v[0] = fmaxf(0.f, (v[0] - m.x) * iv.x);
        v[1] = fmaxf(0.f, (v[1] - m.y) * iv.y);
        v[2] = fmaxf(0.f, (v[2] - m.z) * iv.z);
        v[3] = fmaxf(0.f, (v[3] - m.w) * iv.w);
        __builtin_nontemporal_store(v, ((floatx4*)out) + idx);
    }
}

extern "C" void kernel_launch(void* const* d_in, const int* in_sizes, int n_in,
                              void* d_out, int out_size, void* d_ws, size_t ws_size,
                              hipStream_t stream) {
    const float* atom  = (const float*)d_in[0];
    const float* bond  = (const float*)d_in[1];
    const int*   a1    = (const int*)d_in[2];
    const int*   b1    = (const int*)d_in[3];
    const int*   a2    = (const int*)d_in[4];
    const int*   b2    = (const int*)d_in[5];
    const int*   a3    = (const int*)d_in[6];
    const int*   b3    = (const int*)d_in[7];
    const int*   a4    = (const int*)d_in[8];
    const int*   b4    = (const int*)d_in[9];
    const float* Wself = (const float*)d_in[10];
    const float* W1    = (const float*)d_in[11];
    const float* W2    = (const float*)d_in[12];
    const float* W3    = (const float*)d_in[13];
    const float* W4    = (const float*)d_in[14];
    float* out = (float*)d_out;

    const size_t abf_bytes  = (size_t)N_ATOMS * 128 * sizeof(unsigned short); // 128 MB
    const size_t xbf_bytes  = abf_bytes;                                      // 128 MB
    const size_t pack_bytes = 4 * SEG_ELEMS * sizeof(unsigned short);
    const size_t part_bytes = (size_t)NBLK * 128 * sizeof(float);
    const size_t need_full  = abf_bytes + xbf_bytes + pack_bytes + 2 * part_bytes + 1024;
    const size_t need_bf    = abf_bytes + pack_bytes + 2 * part_bytes + 1024;

    if (ws_size >= need_full) {
        // ws: atom_bf | x_bf | packedW | sumPart | sqPart | mv
        char* p = (char*)d_ws;
        unsigned short* abf     = (unsigned short*)p;  p += abf_bytes;
        unsigned short* xbf     = (unsigned short*)p;  p += xbf_bytes;
        unsigned short* packedW = (unsigned short*)p;  p += pack_bytes;
        float* sumPart = (float*)p;                    p += part_bytes;
        float* sqPart  = (float*)p;                    p += part_bytes;
        float* mv      = (float*)p;

        hipLaunchKernelGGL(gdc_cvt, dim3(2048), dim3(256), 0, stream, atom, abf);
        hipLaunchKernelGGL(gdc_pack, dim3((4*9*8*64 + 255)/256), dim3(256), 0, stream,
                           W1, W2, W3, W4, Wself, packedW);
        hipLaunchKernelGGL((gdc_mfma<true, true>), dim3(NBLK), dim3(512), 0, stream,
                           atom, abf, bond, a1, b1, a2, b2, a3, b3, a4, b4,
                           packedW, out, xbf, sumPart, sqPart);
        hipLaunchKernelGGL(gdc_stats, dim3(128), dim3(256), 0, stream,
                           sumPart, sqPart, mv);
        hipLaunchKernelGGL(gdc_norm_bf, dim3(2048), dim3(256), 0, stream, xbf, out, mv);
    } else if (ws_size >= need_bf) {
        // ws: atom_bf | packedW | sumPart | sqPart | mv  (R15 path)
        char* p = (char*)d_ws;
        unsigned short* abf     = (unsigned short*)p;  p += abf_bytes;
        unsigned short* packedW = (unsigned short*)p;  p += pack_bytes;
        float* sumPart = (float*)p;                    p += part_bytes;
        float* sqPart  = (float*)p;                    p += part_bytes;
        float* mv      = (float*)p;

        hipLaunchKernelGGL(gdc_cvt, dim3(2048), dim3(256), 0, stream, atom, abf);
        hipLaunchKernelGGL(gdc_pack, dim3((4*9*8*64 + 255)/256), dim3(256), 0, stream,
                           W1, W2, W3, W4, Wself, packedW);
        hipLaunchKernelGGL((gdc_mfma<true, false>), dim3(NBLK), dim3(512), 0, stream,
                           atom, abf, bond, a1, b1, a2, b2, a3, b3, a4, b4,
                           packedW, out, (unsigned short*)nullptr, sumPart, sqPart);
        hipLaunchKernelGGL(gdc_stats, dim3(128), dim3(256), 0, stream,
                           sumPart, sqPart, mv);
        hipLaunchKernelGGL(gdc_norm, dim3(2048), dim3(256), 0, stream, out, mv);
    } else {
        // minimal fallback: f32 gather, f32 in-place norm
        char* p = (char*)d_ws;
        unsigned short* packedW = (unsigned short*)p;  p += pack_bytes;
        float* sumPart = (float*)p;                    p += part_bytes;
        float* sqPart  = (float*)p;                    p += part_bytes;
        float* mv      = (float*)p;

        hipLaunchKernelGGL(gdc_pack, dim3((4*9*8*64 + 255)/256), dim3(256), 0, stream,
                           W1, W2, W3, W4, Wself, packedW);
        hipLaunchKernelGGL((gdc_mfma<false, false>), dim3(NBLK), dim3(512), 0, stream,
                           atom, (const unsigned short*)nullptr, bond,
                           a1, b1, a2, b2, a3, b3, a4, b4,
                           packedW, out, (unsigned short*)nullptr, sumPart, sqPart);
        hipLaunchKernelGGL(gdc_stats, dim3(128), dim3(256), 0, stream,
                           sumPart, sqPart, mv);
        hipLaunchKernelGGL(gdc_norm, dim3(2048), dim3(256), 0, stream, out, mv);
    }
}